// Round 1
// 795.619 us; speedup vs baseline: 1.1000x; 1.1000x over previous
//
#include <hip/hip_runtime.h>
#include <hip/hip_bf16.h>
#include <stdint.h>

typedef __bf16 bf16_t;
typedef __bf16 bf16x4 __attribute__((ext_vector_type(4)));
typedef __bf16 bf16x8 __attribute__((ext_vector_type(8)));
typedef float  f32x4  __attribute__((ext_vector_type(4)));

#define AS_G __attribute__((address_space(1)))
#define AS_L __attribute__((address_space(3)))

// ---------------- fp32 -> bf16 cast (vectorized, exact-cover grid) ----------------
__global__ void cast_f32_bf16(const float* __restrict__ src, bf16_t* __restrict__ dst) {
    int i = blockIdx.x * 256 + threadIdx.x;          // each thread: 4 elements
    float4 v = ((const float4*)src)[i];
    bf16x4 o;
    o.x = (bf16_t)v.x; o.y = (bf16_t)v.y; o.z = (bf16_t)v.z; o.w = (bf16_t)v.w;
    ((bf16x4*)dst)[i] = o;
}

// ---------------- bf16 GEMM: C[M,N] = A[M,K] * Bt[N,K]^T + bias ----------------
// 256x256 tile, BK=32, 512 threads = 8 waves (2M x 4N), each wave 128x64 via 8x4
// MFMA 16x16x32. Ring of 4 LDS buffers (128 KiB), 3-tile-deep prefetch with
// counted s_waitcnt vmcnt(8) + ONE barrier per K-step (T3+T4). LDS XOR-swizzle
// (T2) applied as inverse-swizzled global source (global_load_lds dest must be
// linear) + swizzled ds_read. setprio around MFMA cluster (T5). XCD-aware
// bijective block swizzle (T1): all n-blocks of an m-panel on one XCD.
// Requires: M%256==0, N%256==0, K%32==0, K>=96, gridDim.x%8==0.
template<int OUT_BF16>
__global__ __launch_bounds__(512, 2)
void gemm_bt_kernel(const bf16_t* __restrict__ A,
                    const bf16_t* __restrict__ Bt,
                    const float* __restrict__ bias,
                    void* __restrict__ Cout,
                    int M, int N, int K) {
    __shared__ bf16_t smem[4][2][256 * 32];          // [ring buf][A,B][256 rows x 32 k] = 128 KiB

    const int tid  = threadIdx.x;
    const int wave = tid >> 6, lane = tid & 63;
    const int quad = lane >> 4, r16 = lane & 15;
    const int wr = wave >> 2, wc = wave & 3;         // 2 x 4 wave grid

    // T1: XCD-aware bijective swizzle (gridDim.x divisible by 8 by construction)
    const int nbx = N >> 8;                          // n-blocks
    const int cpx = gridDim.x >> 3;
    const int swz = (blockIdx.x & 7) * cpx + (blockIdx.x >> 3);
    const int m0 = (swz / nbx) << 8;
    const int n0 = (swz % nbx) << 8;

    // ---- staging precompute: thread owns 16B chunks c0=tid, c1=512+tid of each 16 KB tile.
    // LDS dest is LINEAR (chunk*16B). Global source k-chunk is inverse-swizzled so the
    // swizzled reader sees the right data (rule #21).
    const int c0 = tid, c1 = 512 + tid;
    const int r0 = c0 >> 2, cc0 = c0 & 3;
    const int r1 = c1 >> 2, cc1 = c1 & 3;
    const int s0 = (r0 & 3) ^ ((r0 >> 2) & 3);
    const int s1 = (r1 & 3) ^ ((r1 >> 2) & 3);
    const bf16_t* gA0 = A  + (size_t)(m0 + r0) * K + ((cc0 ^ s0) << 3);
    const bf16_t* gA1 = A  + (size_t)(m0 + r1) * K + ((cc1 ^ s1) << 3);
    const bf16_t* gB0 = Bt + (size_t)(n0 + r0) * K + ((cc0 ^ s0) << 3);
    const bf16_t* gB1 = Bt + (size_t)(n0 + r1) * K + ((cc1 ^ s1) << 3);

#define STAGE(bufi, kt) do {                                                                    \
        const int _ko = (kt) << 5;                                                              \
        __builtin_amdgcn_global_load_lds((AS_G void*)(gA0 + _ko), (AS_L void*)(&smem[bufi][0][c0 * 8]), 16, 0, 0); \
        __builtin_amdgcn_global_load_lds((AS_G void*)(gA1 + _ko), (AS_L void*)(&smem[bufi][0][c1 * 8]), 16, 0, 0); \
        __builtin_amdgcn_global_load_lds((AS_G void*)(gB0 + _ko), (AS_L void*)(&smem[bufi][1][c0 * 8]), 16, 0, 0); \
        __builtin_amdgcn_global_load_lds((AS_G void*)(gB1 + _ko), (AS_L void*)(&smem[bufi][1][c1 * 8]), 16, 0, 0); \
    } while (0)

    f32x4 acc[8][4] = {};
    const int NT = K >> 5;

    // prologue: 3-deep prefetch (12 loads in flight)
    STAGE(0, 0); STAGE(1, 1); STAGE(2, 2);

    // ---- swizzled fragment read offsets (per-lane constant: wr*128/t*16 are 0 mod 16,
    // so row&3 == r16&3 and (row>>2)&3 == (r16>>2)&3 for every fragment row)
    const int swzc = quad ^ (r16 & 3) ^ ((r16 >> 2) & 3);
    const int aoff = ((wr * 128 + r16) << 5) + (swzc << 3);   // elements; row stride 32
    const int boff = ((wc * 64  + r16) << 5) + (swzc << 3);

    for (int t = 0; t < NT; ++t) {
        // counted wait: tiles t..t+2 in flight (12 loads max); keep 8 in flight,
        // guarantee tile t's 4 loads (oldest) are done. Barrier fused in one asm so
        // nothing is scheduled between them; "memory" pins all LDS/global ops.
        asm volatile("s_waitcnt vmcnt(8)\n\ts_barrier" ::: "memory");

        if (t + 3 < NT) STAGE((t + 3) & 3, t + 3);   // into buf (t-1)&3: reads done pre-barrier

        const bf16_t* pA = &smem[t & 3][0][0];
        const bf16_t* pB = &smem[t & 3][1][0];
        bf16x8 aF[8], bF[4];
#pragma unroll
        for (int i = 0; i < 8; ++i) aF[i] = *(const bf16x8*)(pA + aoff + i * 512);
#pragma unroll
        for (int i = 0; i < 4; ++i) bF[i] = *(const bf16x8*)(pB + boff + i * 512);

        __builtin_amdgcn_s_setprio(1);
#pragma unroll
        for (int tm = 0; tm < 8; ++tm)
#pragma unroll
            for (int tn = 0; tn < 4; ++tn)
                acc[tm][tn] = __builtin_amdgcn_mfma_f32_16x16x32_bf16(aF[tm], bF[tn], acc[tm][tn], 0, 0, 0);
        __builtin_amdgcn_s_setprio(0);
    }
#undef STAGE

    float bv[4];
#pragma unroll
    for (int tn = 0; tn < 4; ++tn) bv[tn] = bias[n0 + wc * 64 + tn * 16 + r16];

#pragma unroll
    for (int tm = 0; tm < 8; ++tm) {
#pragma unroll
        for (int r = 0; r < 4; ++r) {
            const int m = m0 + wr * 128 + tm * 16 + quad * 4 + r;
#pragma unroll
            for (int tn = 0; tn < 4; ++tn) {
                const int n = n0 + wc * 64 + tn * 16 + r16;
                const float v = acc[tm][tn][r] + bv[tn];
                if (OUT_BF16) ((bf16_t*)Cout)[(size_t)m * N + n] = (bf16_t)v;
                else          ((float*)Cout)[(size_t)m * N + n]  = v;
            }
        }
    }
}

// ---------------- attention: one wave per (b,a) position ----------------
// scores (16x16) = QK^T/12 via 2 MFMAs from global; sparsemax over g (16) via
// per-lane bitonic network; PV via zero-padded MFMA per 16-wide e-chunk; write
// into M2 with the torch transpose(1,2).view(B,-1,D) scramble folded in:
//   r = h*256 + a>>4, c = (a&15)*64 + e, m2 = r*8 + b.
__global__ void attn_kernel(const bf16_t* __restrict__ Q, const bf16_t* __restrict__ K,
                            const bf16_t* __restrict__ V, bf16_t* __restrict__ M2) {
    __shared__ float zs_s[4][16][17];
    __shared__ float tau_s[4][16];
    const int wave = threadIdx.x >> 6, lane = threadIdx.x & 63;
    const int quad = lane >> 4, g16 = lane & 15;
    const int p = blockIdx.x * 4 + wave;        // p = a*8 + b  (row index of Q/K/V)
    const int a = p >> 3, b = p & 7;
    const bf16_t* q = Q + (size_t)p * 1024;
    const bf16_t* k = K + (size_t)p * 1024;
    const bf16_t* v = V + (size_t)p * 1024;

    // QK^T: A-frag = Q[h=lane&15][k=quad*8+j], B-frag = K[g=lane&15][k=quad*8+j]
    bf16x8 qa0 = *(const bf16x8*)(q + g16 * 64 + quad * 8);
    bf16x8 qa1 = *(const bf16x8*)(q + g16 * 64 + 32 + quad * 8);
    bf16x8 ka0 = *(const bf16x8*)(k + g16 * 64 + quad * 8);
    bf16x8 ka1 = *(const bf16x8*)(k + g16 * 64 + 32 + quad * 8);
    f32x4 sc = {0.f, 0.f, 0.f, 0.f};
    sc = __builtin_amdgcn_mfma_f32_16x16x32_bf16(qa0, ka0, sc, 0, 0, 0);
    sc = __builtin_amdgcn_mfma_f32_16x16x32_bf16(qa1, ka1, sc, 0, 0, 0);

    const float inv = 1.0f / 12.0f;  // 1/(sqrt(64) * alpha=1.5)
#pragma unroll
    for (int r = 0; r < 4; ++r) zs_s[wave][quad * 4 + r][g16] = sc[r] * inv;   // row h=quad*4+r, col g=lane&15
    __syncthreads();

    if (lane < 16) {   // lane = row h; serial sparsemax on 16 values (all constant-indexed -> VGPRs)
        float z[16];
#pragma unroll
        for (int j = 0; j < 16; ++j) z[j] = zs_s[wave][lane][j];
        // bitonic sort, descending
#pragma unroll
        for (int kk = 2; kk <= 16; kk <<= 1) {
#pragma unroll
            for (int j = kk >> 1; j > 0; j >>= 1) {
#pragma unroll
                for (int i = 0; i < 16; ++i) {
                    int ixj = i ^ j;
                    if (ixj > i) {
                        bool desc = ((i & kk) == 0);
                        float zi = z[i], zj = z[ixj];
                        bool sw = desc ? (zi < zj) : (zi > zj);
                        z[i]   = sw ? zj : zi;
                        z[ixj] = sw ? zi : zj;
                    }
                }
            }
        }
        float cum = 0.f, csel = 0.f;
        int ksel = 1;
#pragma unroll
        for (int j = 0; j < 16; ++j) {
            cum += z[j];
            bool sup = z[j] * (float)(j + 1) > (cum - 1.0f);   // z_sorted - (cumsum-1)/r > 0
            ksel = sup ? (j + 1) : ksel;
            csel = sup ? cum : csel;
        }
        tau_s[wave][lane] = (csel - 1.0f) / (float)ksel;
    }
    __syncthreads();

    // attn = max(zs - tau[h], 0), stored [h][g] for A-frag reads
#pragma unroll
    for (int r = 0; r < 4; ++r) {
        float av = sc[r] * inv - tau_s[wave][quad * 4 + r];
        zs_s[wave][quad * 4 + r][g16] = av > 0.f ? av : 0.f;
    }
    __syncthreads();

    // PV: A-frag attn[m=lane&15][k=quad*8+j], k>=16 -> 0 (quads 2,3)
    bf16x8 aP;
#pragma unroll
    for (int j = 0; j < 8; ++j) {
        float f = (quad < 2) ? zs_s[wave][g16][quad * 8 + j] : 0.f;
        aP[j] = (bf16_t)f;
    }
#pragma unroll
    for (int c = 0; c < 4; ++c) {     // e-chunks of 16
        bf16x8 bV;
#pragma unroll
        for (int j = 0; j < 8; ++j) {  // B-frag: V[k=g=quad*8+j][n=e0+lane&15], g>=16 -> 0
            int g = quad * 8 + j;
            bV[j] = (quad < 2) ? v[g * 64 + c * 16 + g16] : (bf16_t)0.f;
        }
        f32x4 oc = {0.f, 0.f, 0.f, 0.f};
        oc = __builtin_amdgcn_mfma_f32_16x16x32_bf16(aP, bV, oc, 0, 0, 0);
#pragma unroll
        for (int r = 0; r < 4; ++r) {
            int h = quad * 4 + r;
            int e = c * 16 + g16;
            int rr = (h << 8) + (a >> 4);
            int c2 = ((a & 15) << 6) + e;
            M2[((size_t)(rr * 8 + b)) * 1024 + c2] = (bf16_t)oc[r];
        }
    }
}

// ---------------- launch ----------------
extern "C" void kernel_launch(void* const* d_in, const int* in_sizes, int n_in,
                              void* d_out, int out_size, void* d_ws, size_t ws_size,
                              hipStream_t stream) {
    (void)in_sizes; (void)n_in; (void)out_size; (void)ws_size;
    const float* query = (const float*)d_in[0];
    const float* key   = (const float*)d_in[1];
    const float* value = (const float*)d_in[2];
    const float* Wq = (const float*)d_in[3];
    const float* bq = (const float*)d_in[4];
    const float* Wk = (const float*)d_in[5];
    const float* bk = (const float*)d_in[6];
    const float* Wv = (const float*)d_in[7];
    const float* bv = (const float*)d_in[8];
    const float* Wo = (const float*)d_in[9];
    const float* bo = (const float*)d_in[10];

    const int M = 32768, D = 1024;
    const size_t MD = (size_t)M * D;

    uint8_t* ws = (uint8_t*)d_ws;
    bf16_t* abuf = (bf16_t*)ws;                 // reused cast buffer (64 MiB)
    bf16_t* Qb   = (bf16_t*)(ws + MD * 2);
    bf16_t* Kb   = Qb + MD;
    bf16_t* Vb   = Kb + MD;
    bf16_t* M2   = Vb + MD;
    bf16_t* Wqb  = M2 + MD;
    bf16_t* Wkb  = Wqb + (size_t)D * D;
    bf16_t* Wvb  = Wkb + (size_t)D * D;
    bf16_t* Wob  = Wvb + (size_t)D * D;

    const int wBlocks = D * D / 1024;           // 1024
    const int aBlocks = (int)(MD / 1024);       // 32768
    cast_f32_bf16<<<wBlocks, 256, 0, stream>>>(Wq, Wqb);
    cast_f32_bf16<<<wBlocks, 256, 0, stream>>>(Wk, Wkb);
    cast_f32_bf16<<<wBlocks, 256, 0, stream>>>(Wv, Wvb);
    cast_f32_bf16<<<wBlocks, 256, 0, stream>>>(Wo, Wob);

    const int gblk = (M / 256) * (D / 256);     // 512 blocks, %8==0 for XCD swizzle

    cast_f32_bf16<<<aBlocks, 256, 0, stream>>>(query, abuf);
    gemm_bt_kernel<1><<<gblk, 512, 0, stream>>>(abuf, Wqb, bq, Qb, M, D, D);
    cast_f32_bf16<<<aBlocks, 256, 0, stream>>>(key, abuf);
    gemm_bt_kernel<1><<<gblk, 512, 0, stream>>>(abuf, Wkb, bk, Kb, M, D, D);
    cast_f32_bf16<<<aBlocks, 256, 0, stream>>>(value, abuf);
    gemm_bt_kernel<1><<<gblk, 512, 0, stream>>>(abuf, Wvb, bv, Vb, M, D, D);

    attn_kernel<<<M / 4, 256, 0, stream>>>(Qb, Kb, Vb, M2);

    gemm_bt_kernel<0><<<gblk, 512, 0, stream>>>(M2, Wob, bo, (float*)d_out, M, D, D);
}

// Round 3
// 783.720 us; speedup vs baseline: 1.1167x; 1.0152x over previous
//
#include <hip/hip_runtime.h>
#include <hip/hip_bf16.h>
#include <stdint.h>

typedef __bf16 bf16_t;
typedef __bf16 bf16x4 __attribute__((ext_vector_type(4)));
typedef __bf16 bf16x8 __attribute__((ext_vector_type(8)));
typedef float  f32x4  __attribute__((ext_vector_type(4)));

#define AS_G __attribute__((address_space(1)))
#define AS_L __attribute__((address_space(3)))

// ---------------- fp32 -> bf16 cast (vectorized, exact-cover grid) ----------------
__global__ void cast_f32_bf16(const float* __restrict__ src, bf16_t* __restrict__ dst) {
    int i = blockIdx.x * 256 + threadIdx.x;          // each thread: 4 elements
    float4 v = ((const float4*)src)[i];
    bf16x4 o;
    o.x = (bf16_t)v.x; o.y = (bf16_t)v.y; o.z = (bf16_t)v.z; o.w = (bf16_t)v.w;
    ((bf16x4*)dst)[i] = o;
}

// ---------------- bf16 GEMM: C[M,N] = A[M,K] * Bt[N,K]^T + bias ----------------
// 256x256 tile, BK=64, 512 threads = 8 waves (2M x 4N), each wave 128x64.
// Double-buffered LDS (128 KiB). Per K-tile: stage ALL 8 next-tile loads at top,
// s_waitcnt vmcnt(8) (counted, never 0 mid-loop), raw s_barrier (no compiler
// drain), then FOUR sched_barrier-pinned phases of {ds_read subtile -> setprio(1)
// 16 MFMA setprio(0)} so ds_read latency of phase p+1 overlaps MFMA of phase p
// across the 2 waves/SIMD. End-of-iter barrier protects buffer WAR.
// LDS XOR-swizzle: 16B chunk j of a 128B row stored at slot j^(row&7); staging
// reads the inverse-permuted global chunk (both-sides involution, rule #21).
// Requires: M%256==0, N%256==0, K%64==0, gridDim.x%8==0.
template<int OUT_BF16>
__global__ __launch_bounds__(512, 2)
void gemm_bt_kernel(const bf16_t* __restrict__ A,
                    const bf16_t* __restrict__ Bt,
                    const float* __restrict__ bias,
                    void* __restrict__ Cout,
                    int M, int N, int K) {
    __shared__ bf16_t smem[2][2][256 * 64];          // [dbuf][A,B][256 rows x 64 k] = 128 KiB

    const int tid  = threadIdx.x;
    const int wave = tid >> 6, lane = tid & 63;
    const int quad = lane >> 4, r16 = lane & 15;
    const int wr = wave >> 2, wc = wave & 3;         // 2 x 4 wave grid

    // T1: XCD-aware bijective swizzle (gridDim.x divisible by 8 by construction)
    const int nbx = N >> 8;
    const int cpx = gridDim.x >> 3;
    const int swz = (blockIdx.x & 7) * cpx + (blockIdx.x >> 3);
    const int m0 = (swz / nbx) << 8;
    const int n0 = (swz % nbx) << 8;

    // ---- staging: thread owns 16B chunks c_u = tid + u*512 (u=0..3) of each 32 KB tile
    // (same chunk ids for A and B). LDS dest is LINEAR (chunk*16B); global source
    // k-chunk is kc = (c&7) ^ ((c>>3)&7) so the swizzled reader sees logical order.
    const int cc[4] = { tid, tid + 512, tid + 1024, tid + 1536 };
    const bf16_t* gA[4]; const bf16_t* gB[4];
#pragma unroll
    for (int u = 0; u < 4; ++u) {
        const int row = cc[u] >> 3;
        const int kc  = (cc[u] & 7) ^ (row & 7);
        gA[u] = A  + (size_t)(m0 + row) * K + (kc << 3);
        gB[u] = Bt + (size_t)(n0 + row) * K + (kc << 3);
    }

#define STAGE(bufi, kt) do {                                                                      \
        const int _ko = (kt) << 6;                                                                \
        __builtin_amdgcn_global_load_lds((AS_G void*)(gA[0] + _ko), (AS_L void*)(&smem[bufi][0][cc[0] * 8]), 16, 0, 0); \
        __builtin_amdgcn_global_load_lds((AS_G void*)(gA[1] + _ko), (AS_L void*)(&smem[bufi][0][cc[1] * 8]), 16, 0, 0); \
        __builtin_amdgcn_global_load_lds((AS_G void*)(gA[2] + _ko), (AS_L void*)(&smem[bufi][0][cc[2] * 8]), 16, 0, 0); \
        __builtin_amdgcn_global_load_lds((AS_G void*)(gA[3] + _ko), (AS_L void*)(&smem[bufi][0][cc[3] * 8]), 16, 0, 0); \
        __builtin_amdgcn_global_load_lds((AS_G void*)(gB[0] + _ko), (AS_L void*)(&smem[bufi][1][cc[0] * 8]), 16, 0, 0); \
        __builtin_amdgcn_global_load_lds((AS_G void*)(gB[1] + _ko), (AS_L void*)(&smem[bufi][1][cc[1] * 8]), 16, 0, 0); \
        __builtin_amdgcn_global_load_lds((AS_G void*)(gB[2] + _ko), (AS_L void*)(&smem[bufi][1][cc[2] * 8]), 16, 0, 0); \
        __builtin_amdgcn_global_load_lds((AS_G void*)(gB[3] + _ko), (AS_L void*)(&smem[bufi][1][cc[3] * 8]), 16, 0, 0); \
    } while (0)

    // ---- swizzled fragment read offsets (elements). row&7 == r16&7 for every
    // fragment row (wr*128, wc*64, tm*16 all 0 mod 8), so the XOR is lane-constant.
    const int arow = wr * 128 + r16;
    const int brow = wc * 64  + r16;
    const int sw0 = (0 | quad) ^ (r16 & 7);          // k-slice 0 chunk slot
    const int sw1 = (4 | quad) ^ (r16 & 7);          // k-slice 1 chunk slot
    const int aoff0 = arow * 64 + sw0 * 8, aoff1 = arow * 64 + sw1 * 8;
    const int boff0 = brow * 64 + sw0 * 8, boff1 = brow * 64 + sw1 * 8;

    f32x4 acc[8][4] = {};
    const int NT = K >> 6;

    STAGE(0, 0);                                     // prologue

    for (int t = 0; t < NT; ++t) {
        if (t + 1 < NT) {
            STAGE((t + 1) & 1, t + 1);               // 8 loads into the buffer freed last iter
            asm volatile("s_waitcnt vmcnt(8)" ::: "memory");   // tile t complete; 8 in flight
        } else {
            asm volatile("s_waitcnt vmcnt(0)" ::: "memory");   // final tile: drain once
        }
        __builtin_amdgcn_s_barrier();                // raw barrier: no compiler vmcnt drain
        __builtin_amdgcn_sched_barrier(0);

        const bf16_t* pA = &smem[t & 1][0][0];
        const bf16_t* pB = &smem[t & 1][1][0];
        bf16x8 b0[4], a0[4], a1[4], b1[4], a2[4], a3[4];

        // ---- phase 0: k-slice 0, tm 0-3 (8 reads, 16 MFMA)
#pragma unroll
        for (int i = 0; i < 4; ++i) b0[i] = *(const bf16x8*)(pB + boff0 + i * 1024);
#pragma unroll
        for (int i = 0; i < 4; ++i) a0[i] = *(const bf16x8*)(pA + aoff0 + i * 1024);
        __builtin_amdgcn_s_setprio(1);
#pragma unroll
        for (int tm = 0; tm < 4; ++tm)
#pragma unroll
            for (int tn = 0; tn < 4; ++tn)
                acc[tm][tn] = __builtin_amdgcn_mfma_f32_16x16x32_bf16(a0[tm], b0[tn], acc[tm][tn], 0, 0, 0);
        __builtin_amdgcn_s_setprio(0);
        __builtin_amdgcn_sched_barrier(0);

        // ---- phase 1: k-slice 0, tm 4-7 (4 reads, 16 MFMA)
#pragma unroll
        for (int i = 0; i < 4; ++i) a1[i] = *(const bf16x8*)(pA + aoff0 + (4 + i) * 1024);
        __builtin_amdgcn_s_setprio(1);
#pragma unroll
        for (int tm = 0; tm < 4; ++tm)
#pragma unroll
            for (int tn = 0; tn < 4; ++tn)
                acc[4 + tm][tn] = __builtin_amdgcn_mfma_f32_16x16x32_bf16(a1[tm], b0[tn], acc[4 + tm][tn], 0, 0, 0);
        __builtin_amdgcn_s_setprio(0);
        __builtin_amdgcn_sched_barrier(0);

        // ---- phase 2: k-slice 1, tm 0-3 (8 reads, 16 MFMA)
#pragma unroll
        for (int i = 0; i < 4; ++i) b1[i] = *(const bf16x8*)(pB + boff1 + i * 1024);
#pragma unroll
        for (int i = 0; i < 4; ++i) a2[i] = *(const bf16x8*)(pA + aoff1 + i * 1024);
        __builtin_amdgcn_s_setprio(1);
#pragma unroll
        for (int tm = 0; tm < 4; ++tm)
#pragma unroll
            for (int tn = 0; tn < 4; ++tn)
                acc[tm][tn] = __builtin_amdgcn_mfma_f32_16x16x32_bf16(a2[tm], b1[tn], acc[tm][tn], 0, 0, 0);
        __builtin_amdgcn_s_setprio(0);
        __builtin_amdgcn_sched_barrier(0);

        // ---- phase 3: k-slice 1, tm 4-7 (4 reads, 16 MFMA)
#pragma unroll
        for (int i = 0; i < 4; ++i) a3[i] = *(const bf16x8*)(pA + aoff1 + (4 + i) * 1024);
        __builtin_amdgcn_s_setprio(1);
#pragma unroll
        for (int tm = 0; tm < 4; ++tm)
#pragma unroll
            for (int tn = 0; tn < 4; ++tn)
                acc[4 + tm][tn] = __builtin_amdgcn_mfma_f32_16x16x32_bf16(a3[tm], b1[tn], acc[4 + tm][tn], 0, 0, 0);
        __builtin_amdgcn_s_setprio(0);
        __builtin_amdgcn_sched_barrier(0);

        __builtin_amdgcn_s_barrier();                // all reads of buf[t&1] done -> next iter may overwrite
        __builtin_amdgcn_sched_barrier(0);
    }
#undef STAGE

    float bv[4];
#pragma unroll
    for (int tn = 0; tn < 4; ++tn) bv[tn] = bias[n0 + wc * 64 + tn * 16 + r16];

#pragma unroll
    for (int tm = 0; tm < 8; ++tm) {
#pragma unroll
        for (int r = 0; r < 4; ++r) {
            const int m = m0 + wr * 128 + tm * 16 + quad * 4 + r;
#pragma unroll
            for (int tn = 0; tn < 4; ++tn) {
                const int n = n0 + wc * 64 + tn * 16 + r16;
                const float v = acc[tm][tn][r] + bv[tn];
                if (OUT_BF16) ((bf16_t*)Cout)[(size_t)m * N + n] = (bf16_t)v;
                else          ((float*)Cout)[(size_t)m * N + n]  = v;
            }
        }
    }
}

// ---------------- attention: one wave per (b,a) position ----------------
__global__ void attn_kernel(const bf16_t* __restrict__ Q, const bf16_t* __restrict__ K,
                            const bf16_t* __restrict__ V, bf16_t* __restrict__ M2) {
    __shared__ float zs_s[4][16][17];
    __shared__ float tau_s[4][16];
    const int wave = threadIdx.x >> 6, lane = threadIdx.x & 63;
    const int quad = lane >> 4, g16 = lane & 15;
    const int p = blockIdx.x * 4 + wave;        // p = a*8 + b  (row index of Q/K/V)
    const int a = p >> 3, b = p & 7;
    const bf16_t* q = Q + (size_t)p * 1024;
    const bf16_t* k = K + (size_t)p * 1024;
    const bf16_t* v = V + (size_t)p * 1024;

    bf16x8 qa0 = *(const bf16x8*)(q + g16 * 64 + quad * 8);
    bf16x8 qa1 = *(const bf16x8*)(q + g16 * 64 + 32 + quad * 8);
    bf16x8 ka0 = *(const bf16x8*)(k + g16 * 64 + quad * 8);
    bf16x8 ka1 = *(const bf16x8*)(k + g16 * 64 + 32 + quad * 8);
    f32x4 sc = {0.f, 0.f, 0.f, 0.f};
    sc = __builtin_amdgcn_mfma_f32_16x16x32_bf16(qa0, ka0, sc, 0, 0, 0);
    sc = __builtin_amdgcn_mfma_f32_16x16x32_bf16(qa1, ka1, sc, 0, 0, 0);

    const float inv = 1.0f / 12.0f;  // 1/(sqrt(64) * alpha=1.5)
#pragma unroll
    for (int r = 0; r < 4; ++r) zs_s[wave][quad * 4 + r][g16] = sc[r] * inv;
    __syncthreads();

    if (lane < 16) {
        float z[16];
#pragma unroll
        for (int j = 0; j < 16; ++j) z[j] = zs_s[wave][lane][j];
#pragma unroll
        for (int kk = 2; kk <= 16; kk <<= 1) {
#pragma unroll
            for (int j = kk >> 1; j > 0; j >>= 1) {
#pragma unroll
                for (int i = 0; i < 16; ++i) {
                    int ixj = i ^ j;
                    if (ixj > i) {
                        bool desc = ((i & kk) == 0);
                        float zi = z[i], zj = z[ixj];
                        bool sw = desc ? (zi < zj) : (zi > zj);
                        z[i]   = sw ? zj : zi;
                        z[ixj] = sw ? zi : zj;
                    }
                }
            }
        }
        float cum = 0.f, csel = 0.f;
        int ksel = 1;
#pragma unroll
        for (int j = 0; j < 16; ++j) {
            cum += z[j];
            bool sup = z[j] * (float)(j + 1) > (cum - 1.0f);
            ksel = sup ? (j + 1) : ksel;
            csel = sup ? cum : csel;
        }
        tau_s[wave][lane] = (csel - 1.0f) / (float)ksel;
    }
    __syncthreads();

#pragma unroll
    for (int r = 0; r < 4; ++r) {
        float av = sc[r] * inv - tau_s[wave][quad * 4 + r];
        zs_s[wave][quad * 4 + r][g16] = av > 0.f ? av : 0.f;
    }
    __syncthreads();

    bf16x8 aP;
#pragma unroll
    for (int j = 0; j < 8; ++j) {
        float f = (quad < 2) ? zs_s[wave][g16][quad * 8 + j] : 0.f;
        aP[j] = (bf16_t)f;
    }
#pragma unroll
    for (int c = 0; c < 4; ++c) {
        bf16x8 bV;
#pragma unroll
        for (int j = 0; j < 8; ++j) {
            int g = quad * 8 + j;
            bV[j] = (quad < 2) ? v[g * 64 + c * 16 + g16] : (bf16_t)0.f;
        }
        f32x4 oc = {0.f, 0.f, 0.f, 0.f};
        oc = __builtin_amdgcn_mfma_f32_16x16x32_bf16(aP, bV, oc, 0, 0, 0);
#pragma unroll
        for (int r = 0; r < 4; ++r) {
            int h = quad * 4 + r;
            int e = c * 16 + g16;
            int rr = (h << 8) + (a >> 4);
            int c2 = ((a & 15) << 6) + e;
            M2[((size_t)(rr * 8 + b)) * 1024 + c2] = (bf16_t)oc[r];
        }
    }
}

// ---------------- launch ----------------
extern "C" void kernel_launch(void* const* d_in, const int* in_sizes, int n_in,
                              void* d_out, int out_size, void* d_ws, size_t ws_size,
                              hipStream_t stream) {
    (void)in_sizes; (void)n_in; (void)out_size; (void)ws_size;
    const float* query = (const float*)d_in[0];
    const float* key   = (const float*)d_in[1];
    const float* value = (const float*)d_in[2];
    const float* Wq = (const float*)d_in[3];
    const float* bq = (const float*)d_in[4];
    const float* Wk = (const float*)d_in[5];
    const float* bk = (const float*)d_in[6];
    const float* Wv = (const float*)d_in[7];
    const float* bv = (const float*)d_in[8];
    const float* Wo = (const float*)d_in[9];
    const float* bo = (const float*)d_in[10];

    const int M = 32768, D = 1024;
    const size_t MD = (size_t)M * D;

    uint8_t* ws = (uint8_t*)d_ws;
    bf16_t* abuf = (bf16_t*)ws;                 // reused cast buffer (64 MiB)
    bf16_t* Qb   = (bf16_t*)(ws + MD * 2);
    bf16_t* Kb   = Qb + MD;
    bf16_t* Vb   = Kb + MD;
    bf16_t* M2   = Vb + MD;
    bf16_t* Wqb  = M2 + MD;
    bf16_t* Wkb  = Wqb + (size_t)D * D;
    bf16_t* Wvb  = Wkb + (size_t)D * D;
    bf16_t* Wob  = Wvb + (size_t)D * D;

    const int wBlocks = D * D / 1024;           // 1024
    const int aBlocks = (int)(MD / 1024);       // 32768
    cast_f32_bf16<<<wBlocks, 256, 0, stream>>>(Wq, Wqb);
    cast_f32_bf16<<<wBlocks, 256, 0, stream>>>(Wk, Wkb);
    cast_f32_bf16<<<wBlocks, 256, 0, stream>>>(Wv, Wvb);
    cast_f32_bf16<<<wBlocks, 256, 0, stream>>>(Wo, Wob);

    const int gblk = (M / 256) * (D / 256);     // 512 blocks, %8==0 for XCD swizzle

    cast_f32_bf16<<<aBlocks, 256, 0, stream>>>(query, abuf);
    gemm_bt_kernel<1><<<gblk, 512, 0, stream>>>(abuf, Wqb, bq, Qb, M, D, D);
    cast_f32_bf16<<<aBlocks, 256, 0, stream>>>(key, abuf);
    gemm_bt_kernel<1><<<gblk, 512, 0, stream>>>(abuf, Wkb, bk, Kb, M, D, D);
    cast_f32_bf16<<<aBlocks, 256, 0, stream>>>(value, abuf);
    gemm_bt_kernel<1><<<gblk, 512, 0, stream>>>(abuf, Wvb, bv, Vb, M, D, D);

    attn_kernel<<<M / 4, 256, 0, stream>>>(Qb, Kb, Vb, M2);

    gemm_bt_kernel<0><<<gblk, 512, 0, stream>>>(M2, Wob, bo, (float*)d_out, M, D, D);
}